// Round 8
// baseline (323.809 us; speedup 1.0000x reference)
//
#include <hip/hip_runtime.h>

typedef unsigned short u16;
typedef _Float16 f16;
typedef __attribute__((ext_vector_type(8))) _Float16 f16x8;
typedef __attribute__((ext_vector_type(4))) float f32x4;

#define B_  8
#define TQ_ 2048
#define TV_ 2048
#define H_  1024

__device__ __forceinline__ u16 f2h(float x) {
    union { f16 h; u16 u; } c; c.h = (f16)x; return c.u;
}
__device__ __forceinline__ float h2f(u16 u) {
    union { u16 u; f16 h; } c; c.u = u; return (float)c.h;
}

__device__ __forceinline__ void gload_lds16(const u16* g, u16* l) {
    typedef __attribute__((address_space(1))) const unsigned short GAS;
    typedef __attribute__((address_space(3))) unsigned short LAS;
    __builtin_amdgcn_global_load_lds((GAS*)g, (LAS*)l, 16, 0, 0);
}

// fp32 -> fp16 contiguous convert
__global__ __launch_bounds__(256) void k_cvt(const float4* __restrict__ x,
                                             ushort4* __restrict__ o) {
    long long i = (long long)blockIdx.x * 256 + threadIdx.x;
    float4 v = x[i];
    ushort4 h;
    h.x = f2h(v.x); h.y = f2h(v.y); h.z = f2h(v.z); h.w = f2h(v.w);
    o[i] = h;
}

#define SBAR() __builtin_amdgcn_sched_barrier(0)

// BM=256, BN=NH*128, BK=64, 8 waves (2M x 4N), double-buffered LDS,
// 2 barriers per K-tile, read-ahead ds_reads, counted vmcnt after the last
// MFMA cluster, setprio, st-swizzled LDS via pre-swizzled global src.
// Static LDA/LDB/K. 1D grid, XCD-compact (z,bm,bn) decode.
// OM: 0 = f32 out (+bias), 1 = f16 out, 2 = f32 out (+bias + fp16 qadd).
template<int NH, int OM, int LDA, int LDB, int KK>
__global__ __launch_bounds__(512, 2) void k_gemm8(const u16* __restrict__ Ap,
                                                  const u16* __restrict__ Bp,
                                                  long long sA, long long sB,
                                                  int mnTiles, int gn,
                                                  void* __restrict__ Cv, long long sC,
                                                  int ldc, const float* __restrict__ bias,
                                                  const u16* __restrict__ qadd) {
    constexpr int BUFU = 16384 + NH * 8192;
    constexpr int NT = KK / 64;
    __shared__ __align__(16) u16 lds[2 * BUFU];

    const int nper = gridDim.x >> 3;
    const int g = (blockIdx.x & 7) * nper + (blockIdx.x >> 3);
    const int z = g / mnTiles;
    const int rem = g - z * mnTiles;
    const int bm = (rem / gn) * 256;
    const int bn = (rem % gn) * (NH * 128);

    const int tid = threadIdx.x;
    const int lane = tid & 63, wid = tid >> 6;
    const int wm = wid >> 2, wn = wid & 3;
    const int l16 = lane & 15, kg = lane >> 4;

    f32x4 acc[8][NH * 2];
    f32x4 zv = {0.f, 0.f, 0.f, 0.f};
#pragma unroll
    for (int i = 0; i < 8; ++i)
#pragma unroll
        for (int j = 0; j < NH * 2; ++j) acc[i][j] = zv;

    const u16* Ab = Ap + (long long)z * sA;
    const u16* Bb = Bp + (long long)z * sB;

    const int jst = (tid & 7) ^ ((tid >> 3) & 7);
    const int rst = tid >> 3;

    auto stageA = [&](int k0, int h, int obase) {
#pragma unroll
        for (int c = 0; c < 2; ++c) {
            int r = h * 128 + c * 64 + rst;
            gload_lds16(Ab + (long long)(bm + r) * LDA + k0 + jst * 8,
                        &lds[obase + h * 8192 + c * 4096 + tid * 8]);
        }
    };
    auto stageB = [&](int k0, int h, int rbase) {
#pragma unroll
        for (int c = 0; c < 2; ++c) {
            int r = h * 128 + c * 64 + rst;
            gload_lds16(Bb + (long long)(bn + r) * LDB + k0 + jst * 8,
                        &lds[rbase + h * 8192 + c * 4096 + tid * 8]);
        }
    };
    auto rdA = [&](int base, int mh, f16x8* dst) {
#pragma unroll
        for (int i = 0; i < 4; ++i) {
            int r = wm * 128 + mh * 64 + i * 16 + l16;
#pragma unroll
            for (int ks = 0; ks < 2; ++ks) {
                int js = (ks * 4 + kg) ^ (r & 7);
                dst[i * 2 + ks] = *(const f16x8*)&lds[base + r * 64 + js * 8];
            }
        }
    };
    auto rdB = [&](int base, int nh, f16x8* dst) {
#pragma unroll
        for (int jn = 0; jn < 2; ++jn) {
            int r = wn * (NH * 32) + nh * 32 + jn * 16 + l16;
#pragma unroll
            for (int ks = 0; ks < 2; ++ks) {
                int js = (ks * 4 + kg) ^ (r & 7);
                dst[jn * 2 + ks] = *(const f16x8*)&lds[base + r * 64 + js * 8];
            }
        }
    };

    // ---- prologue: tile0 (A+B) -> buf0; tile1 B -> buf1
    stageA(0, 0, 0);
    stageA(0, 1, 0);
#pragma unroll
    for (int h = 0; h < NH; ++h) stageB(0, h, 16384);
    if (NT > 1) {
#pragma unroll
        for (int h = 0; h < NH; ++h) stageB(64, h, BUFU + 16384);
        if constexpr (NH == 2) asm volatile("s_waitcnt vmcnt(4)" ::: "memory");
        else                   asm volatile("s_waitcnt vmcnt(2)" ::: "memory");
    } else {
        asm volatile("s_waitcnt vmcnt(0)" ::: "memory");
    }
    __builtin_amdgcn_s_barrier();
    SBAR();

    f16x8 a0[8], a1[8], b0[4], b1[4];
#pragma unroll 1
    for (int t = 0; t < NT; ++t) {
        const int cur = t & 1;
        const int AB = cur * BUFU;
        const int BB = AB + 16384;
        const int OA = (cur ^ 1) * BUFU;
        const bool sa = (t + 1) < NT;
        const bool sb = (t + 2) < NT;
        if constexpr (NH == 2) {
            // ph1: read a0,b0 (deps) + b1 (ahead); stage A0,A1(t+1); MFMA q00+q01
            rdA(AB, 0, a0);
            rdB(BB, 0, b0);
            rdB(BB, 1, b1);
            if (sa) {
                stageA((t + 1) * 64, 0, OA);
                stageA((t + 1) * 64, 1, OA);
            }
            SBAR();
            __builtin_amdgcn_s_setprio(1);
#pragma unroll
            for (int i = 0; i < 4; ++i)
#pragma unroll
                for (int jn = 0; jn < 2; ++jn)
#pragma unroll
                    for (int ks = 0; ks < 2; ++ks)
                        acc[i][jn] = __builtin_amdgcn_mfma_f32_16x16x32_f16(a0[i * 2 + ks], b0[jn * 2 + ks], acc[i][jn], 0, 0, 0);
#pragma unroll
            for (int i = 0; i < 4; ++i)
#pragma unroll
                for (int jn = 0; jn < 2; ++jn)
#pragma unroll
                    for (int ks = 0; ks < 2; ++ks)
                        acc[i][2 + jn] = __builtin_amdgcn_mfma_f32_16x16x32_f16(a0[i * 2 + ks], b1[jn * 2 + ks], acc[i][2 + jn], 0, 0, 0);
            __builtin_amdgcn_s_setprio(0);
            __builtin_amdgcn_s_barrier();
            SBAR();
            // ph2: read a1; stage B0,B1(t+2) over consumed B(t); MFMA q11+q10; vmcnt
            rdA(AB, 1, a1);
            if (sb) {
                stageB((t + 2) * 64, 0, BB);
                stageB((t + 2) * 64, 1, BB);
            }
            SBAR();
            __builtin_amdgcn_s_setprio(1);
#pragma unroll
            for (int i = 0; i < 4; ++i)
#pragma unroll
                for (int jn = 0; jn < 2; ++jn)
#pragma unroll
                    for (int ks = 0; ks < 2; ++ks)
                        acc[4 + i][2 + jn] = __builtin_amdgcn_mfma_f32_16x16x32_f16(a1[i * 2 + ks], b1[jn * 2 + ks], acc[4 + i][2 + jn], 0, 0, 0);
#pragma unroll
            for (int i = 0; i < 4; ++i)
#pragma unroll
                for (int jn = 0; jn < 2; ++jn)
#pragma unroll
                    for (int ks = 0; ks < 2; ++ks)
                        acc[4 + i][jn] = __builtin_amdgcn_mfma_f32_16x16x32_f16(a1[i * 2 + ks], b0[jn * 2 + ks], acc[4 + i][jn], 0, 0, 0);
            __builtin_amdgcn_s_setprio(0);
            if (sb)      asm volatile("s_waitcnt vmcnt(4)" ::: "memory");
            else if (sa) asm volatile("s_waitcnt vmcnt(0)" ::: "memory");
            __builtin_amdgcn_s_barrier();
            SBAR();
        } else {
            // ph1: read a0,b0 (deps) + a1 (ahead); stage A0,A1(t+1); MFMA half 0
            rdA(AB, 0, a0);
            rdB(BB, 0, b0);
            rdA(AB, 1, a1);
            if (sa) {
                stageA((t + 1) * 64, 0, OA);
                stageA((t + 1) * 64, 1, OA);
            }
            SBAR();
            __builtin_amdgcn_s_setprio(1);
#pragma unroll
            for (int i = 0; i < 4; ++i)
#pragma unroll
                for (int jn = 0; jn < 2; ++jn)
#pragma unroll
                    for (int ks = 0; ks < 2; ++ks)
                        acc[i][jn] = __builtin_amdgcn_mfma_f32_16x16x32_f16(a0[i * 2 + ks], b0[jn * 2 + ks], acc[i][jn], 0, 0, 0);
            __builtin_amdgcn_s_setprio(0);
            __builtin_amdgcn_s_barrier();
            SBAR();
            // ph2: stage B(t+2) over consumed B(t); MFMA half 1; vmcnt
            if (sb) stageB((t + 2) * 64, 0, BB);
            SBAR();
            __builtin_amdgcn_s_setprio(1);
#pragma unroll
            for (int i = 0; i < 4; ++i)
#pragma unroll
                for (int jn = 0; jn < 2; ++jn)
#pragma unroll
                    for (int ks = 0; ks < 2; ++ks)
                        acc[4 + i][jn] = __builtin_amdgcn_mfma_f32_16x16x32_f16(a1[i * 2 + ks], b0[jn * 2 + ks], acc[4 + i][jn], 0, 0, 0);
            __builtin_amdgcn_s_setprio(0);
            if (sb)      asm volatile("s_waitcnt vmcnt(2)" ::: "memory");
            else if (sa) asm volatile("s_waitcnt vmcnt(0)" ::: "memory");
            __builtin_amdgcn_s_barrier();
            SBAR();
        }
    }

    // ---- epilogue
    const int colBase = bn + wn * (NH * 32);
    const int rowBase = bm + wm * 128;
#pragma unroll
    for (int mi = 0; mi < 8; ++mi) {
#pragma unroll
        for (int nj = 0; nj < NH * 2; ++nj) {
            int col = colBase + nj * 16 + l16;
            float badd = (OM != 1 && bias) ? bias[col] : 0.f;
#pragma unroll
            for (int r = 0; r < 4; ++r) {
                long long row = rowBase + mi * 16 + kg * 4 + r;
                long long idx = (long long)z * sC + row * (long long)ldc + col;
                float vv = acc[mi][nj][r] + badd;
                if constexpr (OM == 1) {
                    ((u16*)Cv)[idx] = f2h(vv);
                } else if constexpr (OM == 2) {
                    ((float*)Cv)[idx] = vv + h2f(qadd[idx]);
                } else {
                    ((float*)Cv)[idx] = vv;
                }
            }
        }
    }
}

// row softmax: fp32 scores [*, 2048] -> fp16 probs IN PLACE (first 4KB of row)
__global__ __launch_bounds__(256) void k_softmax(float* __restrict__ S) {
    float* row = S + (long long)blockIdx.x * TV_;
    u16* prow = (u16*)row;
    int t = threadIdx.x;
    float4 a = *(const float4*)(row + t * 4);
    float4 c = *(const float4*)(row + 1024 + t * 4);
    float m = fmaxf(fmaxf(fmaxf(a.x, a.y), fmaxf(a.z, a.w)),
                    fmaxf(fmaxf(c.x, c.y), fmaxf(c.z, c.w)));
#pragma unroll
    for (int o = 32; o; o >>= 1) m = fmaxf(m, __shfl_xor(m, o));
    __shared__ float rm[4], rs[4];
    if ((t & 63) == 0) rm[t >> 6] = m;
    __syncthreads();
    m = fmaxf(fmaxf(rm[0], rm[1]), fmaxf(rm[2], rm[3]));
    float e0 = __expf(a.x - m), e1 = __expf(a.y - m), e2 = __expf(a.z - m), e3 = __expf(a.w - m);
    float e4 = __expf(c.x - m), e5 = __expf(c.y - m), e6 = __expf(c.z - m), e7 = __expf(c.w - m);
    float s = ((e0 + e1) + (e2 + e3)) + ((e4 + e5) + (e6 + e7));
#pragma unroll
    for (int o = 32; o; o >>= 1) s += __shfl_xor(s, o);
    if ((t & 63) == 0) rs[t >> 6] = s;
    __syncthreads();
    s = rs[0] + rs[1] + rs[2] + rs[3];
    float inv = 1.f / s;
    ushort4 o0, o1;
    o0.x = f2h(e0 * inv); o0.y = f2h(e1 * inv); o0.z = f2h(e2 * inv); o0.w = f2h(e3 * inv);
    o1.x = f2h(e4 * inv); o1.y = f2h(e5 * inv); o1.z = f2h(e6 * inv); o1.w = f2h(e7 * inv);
    __syncthreads();   // all reads of this row's fp32 data done before overwrite
    *(ushort4*)(prow + t * 4) = o0;
    *(ushort4*)(prow + 1024 + t * 4) = o1;
}

// in-place LayerNorm over rows of 1024 fp32
__global__ __launch_bounds__(256) void k_layernorm(float* __restrict__ O,
                                                   const float* __restrict__ g,
                                                   const float* __restrict__ b) {
    float* row = O + (long long)blockIdx.x * H_;
    int t = threadIdx.x;
    float4 x = *(const float4*)(row + t * 4);
    float s1 = x.x + x.y + x.z + x.w;
    float s2 = x.x * x.x + x.y * x.y + x.z * x.z + x.w * x.w;
#pragma unroll
    for (int o = 32; o; o >>= 1) { s1 += __shfl_xor(s1, o); s2 += __shfl_xor(s2, o); }
    __shared__ float r1[4], r2[4];
    if ((t & 63) == 0) { r1[t >> 6] = s1; r2[t >> 6] = s2; }
    __syncthreads();
    s1 = r1[0] + r1[1] + r1[2] + r1[3];
    s2 = r2[0] + r2[1] + r2[2] + r2[3];
    float mean = s1 * (1.f / H_);
    float var = s2 * (1.f / H_) - mean * mean;
    float rstd = rsqrtf(fmaxf(var, 0.f) + 1e-5f);
    float4 gv = *(const float4*)(g + t * 4);
    float4 bv = *(const float4*)(b + t * 4);
    float4 o;
    o.x = (x.x - mean) * rstd * gv.x + bv.x;
    o.y = (x.y - mean) * rstd * gv.y + bv.y;
    o.z = (x.z - mean) * rstd * gv.z + bv.z;
    o.w = (x.w - mean) * rstd * gv.w + bv.w;
    *(float4*)(row + t * 4) = o;
}

extern "C" void kernel_launch(void* const* d_in, const int* in_sizes, int n_in,
                              void* d_out, int out_size, void* d_ws, size_t ws_size,
                              hipStream_t stream) {
    const float* q     = (const float*)d_in[0];
    const float* v     = (const float*)d_in[1];
    const float* W     = (const float*)d_in[2];
    const float* bias  = (const float*)d_in[3];
    const float* gamma = (const float*)d_in[4];
    const float* beta  = (const float*)d_in[5];
    float* out = (float*)d_out;
    char* ws = (char*)d_ws;

    const long long nQV = (long long)B_ * TQ_ * H_;     // 16,777,216
    const long long nW  = (long long)H_ * 2 * H_;       //  2,097,152

    u16* Qh  = (u16*)ws;         // 32 MiB fp16 query [B*TQ][1024]
    u16* Vh  = Qh + nQV;         // 32 MiB fp16 value [B][TV][1024]
    u16* Wh  = Vh + nQV;         //  4 MiB fp16 W [1024][2048]
    u16* VWT = Wh + nW;          // 32 MiB fp16 (V.Wc^T)^T : [B][1024][TV]
    u16* QW  = VWT + nQV;        // 32 MiB fp16 Q.Wq^T : [B*TQ][1024]
    float* S = (float*)(QW + nQV);   // Zc x 16 MiB fp32 scores (P fp16 in place)
    size_t fixedBytes = (size_t)((char*)S - ws);
    const size_t perZ = (size_t)TQ_ * TV_ * 4;

    int Zc = 1;
    for (int cand = 4; cand >= 1; cand >>= 1) {
        if (fixedBytes + (size_t)cand * perZ <= ws_size) { Zc = cand; break; }
    }

    // converts (all plain fp32->fp16)
    k_cvt<<<dim3(nQV / 4 / 256), dim3(256), 0, stream>>>((const float4*)q, (ushort4*)Qh);
    k_cvt<<<dim3(nQV / 4 / 256), dim3(256), 0, stream>>>((const float4*)v, (ushort4*)Vh);
    k_cvt<<<dim3(nW / 4 / 256),  dim3(256), 0, stream>>>((const float4*)W, (ushort4*)Wh);

    // VWT[z][n][v] = sum_h Wc[n,h] V[z,v,h]   (A=Wc lda=2048, B=Vh ldb=1024)
    k_gemm8<2, 1, 2048, 1024, 1024><<<dim3(256), dim3(512), 0, stream>>>(
        Wh, Vh, 0, (long long)TV_ * H_,
        32, 8, VWT, (long long)H_ * TV_, TV_, nullptr, nullptr);

    // QW = Q.Wq^T fp16  (A=Qh lda=1024, B=Wq=Wh+1024 ldb=2048)
    k_gemm8<2, 1, 1024, 2048, 1024><<<dim3(256), dim3(512), 0, stream>>>(
        Qh, Wh + H_, 0, 0,
        256, 4, QW, 0, H_, nullptr, nullptr);

    for (int c0 = 0; c0 < B_; c0 += Zc) {
        // scores S = Q.V^T  (BN=256, grid Zc*64, K=1024)
        k_gemm8<2, 0, 1024, 1024, 1024><<<dim3(Zc * 64), dim3(512), 0, stream>>>(
            Qh + (long long)c0 * TQ_ * H_, Vh + (long long)c0 * TV_ * H_,
            (long long)TQ_ * H_, (long long)TV_ * H_,
            64, 8, S, (long long)TQ_ * TV_, TV_, nullptr, nullptr);
        // softmax -> fp16 P in place over S
        k_softmax<<<dim3(Zc * TQ_), dim3(256), 0, stream>>>(S);
        // out = P.VWT + bias + QW  (BN=128, A=in-place P lda=4096, K=2048; fp32 out)
        k_gemm8<1, 2, 4096, 2048, 2048><<<dim3(Zc * 64), dim3(512), 0, stream>>>(
            (const u16*)S, VWT + (long long)c0 * H_ * TV_,
            (long long)TQ_ * 4096, (long long)H_ * TV_,
            64, 8, out + (long long)c0 * TQ_ * H_, (long long)TQ_ * H_, H_,
            bias, QW + (long long)c0 * TQ_ * H_);
    }

    k_layernorm<<<dim3(B_ * TQ_), dim3(256), 0, stream>>>(out, gamma, beta);
}

// Round 9
// 323.784 us; speedup vs baseline: 1.0001x; 1.0001x over previous
//
#include <hip/hip_runtime.h>

typedef unsigned short u16;
typedef _Float16 f16;
typedef __attribute__((ext_vector_type(8))) _Float16 f16x8;
typedef __attribute__((ext_vector_type(4))) float f32x4;

#define B_  8
#define TQ_ 2048
#define TV_ 2048
#define H_  1024

__device__ __forceinline__ u16 f2h(float x) {
    union { f16 h; u16 u; } c; c.h = (f16)x; return c.u;
}
__device__ __forceinline__ float h2f(u16 u) {
    union { u16 u; f16 h; } c; c.u = u; return (float)c.h;
}

__device__ __forceinline__ void gload_lds16(const u16* g, u16* l) {
    typedef __attribute__((address_space(1))) const unsigned short GAS;
    typedef __attribute__((address_space(3))) unsigned short LAS;
    __builtin_amdgcn_global_load_lds((GAS*)g, (LAS*)l, 16, 0, 0);
}

// fp32 -> fp16 contiguous convert
__global__ __launch_bounds__(256) void k_cvt(const float4* __restrict__ x,
                                             ushort4* __restrict__ o) {
    long long i = (long long)blockIdx.x * 256 + threadIdx.x;
    float4 v = x[i];
    ushort4 h;
    h.x = f2h(v.x); h.y = f2h(v.y); h.z = f2h(v.z); h.w = f2h(v.w);
    o[i] = h;
}

#define SBAR() __builtin_amdgcn_sched_barrier(0)

// BM=256, BN=NH*128, BK=64, 8 waves (2M x 4N), double-buffered LDS,
// 2 barriers per K-tile, read-ahead ds_reads, counted vmcnt after the last
// MFMA cluster, setprio, st-swizzled LDS via pre-swizzled global src.
// Static LDA/LDB/K. 1D grid, XCD-compact (z,bm,bn) decode.
// OM: 0 = f32 out (+bias), 1 = f16 out, 2 = f32 out (+bias + fp16 qadd).
template<int NH, int OM, int LDA, int LDB, int KK>
__global__ __launch_bounds__(512, 2) void k_gemm8(const u16* __restrict__ Ap,
                                                  const u16* __restrict__ Bp,
                                                  long long sA, long long sB,
                                                  int mnTiles, int gn,
                                                  void* __restrict__ Cv, long long sC,
                                                  int ldc, const float* __restrict__ bias,
                                                  const u16* __restrict__ qadd) {
    constexpr int BUFU = 16384 + NH * 8192;
    constexpr int NT = KK / 64;
    __shared__ __align__(16) u16 lds[2 * BUFU];

    const int nper = gridDim.x >> 3;
    const int g = (blockIdx.x & 7) * nper + (blockIdx.x >> 3);
    const int z = g / mnTiles;
    const int rem = g - z * mnTiles;
    const int bm = (rem / gn) * 256;
    const int bn = (rem % gn) * (NH * 128);

    const int tid = threadIdx.x;
    const int lane = tid & 63, wid = tid >> 6;
    const int wm = wid >> 2, wn = wid & 3;
    const int l16 = lane & 15, kg = lane >> 4;

    f32x4 acc[8][NH * 2];
    f32x4 zv = {0.f, 0.f, 0.f, 0.f};
#pragma unroll
    for (int i = 0; i < 8; ++i)
#pragma unroll
        for (int j = 0; j < NH * 2; ++j) acc[i][j] = zv;

    const u16* Ab = Ap + (long long)z * sA;
    const u16* Bb = Bp + (long long)z * sB;

    const int jst = (tid & 7) ^ ((tid >> 3) & 7);
    const int rst = tid >> 3;

    auto stageA = [&](int k0, int h, int obase) {
#pragma unroll
        for (int c = 0; c < 2; ++c) {
            int r = h * 128 + c * 64 + rst;
            gload_lds16(Ab + (long long)(bm + r) * LDA + k0 + jst * 8,
                        &lds[obase + h * 8192 + c * 4096 + tid * 8]);
        }
    };
    auto stageB = [&](int k0, int h, int rbase) {
#pragma unroll
        for (int c = 0; c < 2; ++c) {
            int r = h * 128 + c * 64 + rst;
            gload_lds16(Bb + (long long)(bn + r) * LDB + k0 + jst * 8,
                        &lds[rbase + h * 8192 + c * 4096 + tid * 8]);
        }
    };
    auto rdA = [&](int base, int mh, f16x8* dst) {
#pragma unroll
        for (int i = 0; i < 4; ++i) {
            int r = wm * 128 + mh * 64 + i * 16 + l16;
#pragma unroll
            for (int ks = 0; ks < 2; ++ks) {
                int js = (ks * 4 + kg) ^ (r & 7);
                dst[i * 2 + ks] = *(const f16x8*)&lds[base + r * 64 + js * 8];
            }
        }
    };
    auto rdB = [&](int base, int nh, f16x8* dst) {
#pragma unroll
        for (int jn = 0; jn < 2; ++jn) {
            int r = wn * (NH * 32) + nh * 32 + jn * 16 + l16;
#pragma unroll
            for (int ks = 0; ks < 2; ++ks) {
                int js = (ks * 4 + kg) ^ (r & 7);
                dst[jn * 2 + ks] = *(const f16x8*)&lds[base + r * 64 + js * 8];
            }
        }
    };

    // ---- prologue: tile0 (A+B) -> buf0; tile1 B -> buf1
    stageA(0, 0, 0);
    stageA(0, 1, 0);
#pragma unroll
    for (int h = 0; h < NH; ++h) stageB(0, h, 16384);
    if (NT > 1) {
#pragma unroll
        for (int h = 0; h < NH; ++h) stageB(64, h, BUFU + 16384);
        if constexpr (NH == 2) asm volatile("s_waitcnt vmcnt(4)" ::: "memory");
        else                   asm volatile("s_waitcnt vmcnt(2)" ::: "memory");
    } else {
        asm volatile("s_waitcnt vmcnt(0)" ::: "memory");
    }
    __builtin_amdgcn_s_barrier();
    SBAR();

    f16x8 a0[8], a1[8], b0[4], b1[4];
#pragma unroll 1
    for (int t = 0; t < NT; ++t) {
        const int cur = t & 1;
        const int AB = cur * BUFU;
        const int BB = AB + 16384;
        const int OA = (cur ^ 1) * BUFU;
        const bool sa = (t + 1) < NT;
        const bool sb = (t + 2) < NT;
        if constexpr (NH == 2) {
            // ph1: read a0,b0 (deps) + b1 (ahead); stage A0,A1(t+1); MFMA q00+q01
            rdA(AB, 0, a0);
            rdB(BB, 0, b0);
            rdB(BB, 1, b1);
            if (sa) {
                stageA((t + 1) * 64, 0, OA);
                stageA((t + 1) * 64, 1, OA);
            }
            SBAR();
            __builtin_amdgcn_s_setprio(1);
#pragma unroll
            for (int i = 0; i < 4; ++i)
#pragma unroll
                for (int jn = 0; jn < 2; ++jn)
#pragma unroll
                    for (int ks = 0; ks < 2; ++ks)
                        acc[i][jn] = __builtin_amdgcn_mfma_f32_16x16x32_f16(a0[i * 2 + ks], b0[jn * 2 + ks], acc[i][jn], 0, 0, 0);
#pragma unroll
            for (int i = 0; i < 4; ++i)
#pragma unroll
                for (int jn = 0; jn < 2; ++jn)
#pragma unroll
                    for (int ks = 0; ks < 2; ++ks)
                        acc[i][2 + jn] = __builtin_amdgcn_mfma_f32_16x16x32_f16(a0[i * 2 + ks], b1[jn * 2 + ks], acc[i][2 + jn], 0, 0, 0);
            __builtin_amdgcn_s_setprio(0);
            __builtin_amdgcn_s_barrier();
            SBAR();
            // ph2: read a1; stage B0,B1(t+2) over consumed B(t); MFMA q11+q10; vmcnt
            rdA(AB, 1, a1);
            if (sb) {
                stageB((t + 2) * 64, 0, BB);
                stageB((t + 2) * 64, 1, BB);
            }
            SBAR();
            __builtin_amdgcn_s_setprio(1);
#pragma unroll
            for (int i = 0; i < 4; ++i)
#pragma unroll
                for (int jn = 0; jn < 2; ++jn)
#pragma unroll
                    for (int ks = 0; ks < 2; ++ks)
                        acc[4 + i][2 + jn] = __builtin_amdgcn_mfma_f32_16x16x32_f16(a1[i * 2 + ks], b1[jn * 2 + ks], acc[4 + i][2 + jn], 0, 0, 0);
#pragma unroll
            for (int i = 0; i < 4; ++i)
#pragma unroll
                for (int jn = 0; jn < 2; ++jn)
#pragma unroll
                    for (int ks = 0; ks < 2; ++ks)
                        acc[4 + i][jn] = __builtin_amdgcn_mfma_f32_16x16x32_f16(a1[i * 2 + ks], b0[jn * 2 + ks], acc[4 + i][jn], 0, 0, 0);
            __builtin_amdgcn_s_setprio(0);
            if (sb)      asm volatile("s_waitcnt vmcnt(4)" ::: "memory");
            else if (sa) asm volatile("s_waitcnt vmcnt(0)" ::: "memory");
            __builtin_amdgcn_s_barrier();
            SBAR();
        } else {
            // ph1: read a0,b0 (deps) + a1 (ahead); stage A0,A1(t+1); MFMA half 0
            rdA(AB, 0, a0);
            rdB(BB, 0, b0);
            rdA(AB, 1, a1);
            if (sa) {
                stageA((t + 1) * 64, 0, OA);
                stageA((t + 1) * 64, 1, OA);
            }
            SBAR();
            __builtin_amdgcn_s_setprio(1);
#pragma unroll
            for (int i = 0; i < 4; ++i)
#pragma unroll
                for (int jn = 0; jn < 2; ++jn)
#pragma unroll
                    for (int ks = 0; ks < 2; ++ks)
                        acc[i][jn] = __builtin_amdgcn_mfma_f32_16x16x32_f16(a0[i * 2 + ks], b0[jn * 2 + ks], acc[i][jn], 0, 0, 0);
            __builtin_amdgcn_s_setprio(0);
            __builtin_amdgcn_s_barrier();
            SBAR();
            // ph2: stage B(t+2) over consumed B(t); MFMA half 1; vmcnt
            if (sb) stageB((t + 2) * 64, 0, BB);
            SBAR();
            __builtin_amdgcn_s_setprio(1);
#pragma unroll
            for (int i = 0; i < 4; ++i)
#pragma unroll
                for (int jn = 0; jn < 2; ++jn)
#pragma unroll
                    for (int ks = 0; ks < 2; ++ks)
                        acc[4 + i][jn] = __builtin_amdgcn_mfma_f32_16x16x32_f16(a1[i * 2 + ks], b0[jn * 2 + ks], acc[4 + i][jn], 0, 0, 0);
            __builtin_amdgcn_s_setprio(0);
            if (sb)      asm volatile("s_waitcnt vmcnt(2)" ::: "memory");
            else if (sa) asm volatile("s_waitcnt vmcnt(0)" ::: "memory");
            __builtin_amdgcn_s_barrier();
            SBAR();
        }
    }

    // ---- epilogue
    const int colBase = bn + wn * (NH * 32);
    const int rowBase = bm + wm * 128;
#pragma unroll
    for (int mi = 0; mi < 8; ++mi) {
#pragma unroll
        for (int nj = 0; nj < NH * 2; ++nj) {
            int col = colBase + nj * 16 + l16;
            float badd = (OM != 1 && bias) ? bias[col] : 0.f;
#pragma unroll
            for (int r = 0; r < 4; ++r) {
                long long row = rowBase + mi * 16 + kg * 4 + r;
                long long idx = (long long)z * sC + row * (long long)ldc + col;
                float vv = acc[mi][nj][r] + badd;
                if constexpr (OM == 1) {
                    ((u16*)Cv)[idx] = f2h(vv);
                } else if constexpr (OM == 2) {
                    ((float*)Cv)[idx] = vv + h2f(qadd[idx]);
                } else {
                    ((float*)Cv)[idx] = vv;
                }
            }
        }
    }
}

// row softmax: fp32 scores [*, 2048] -> fp16 probs IN PLACE (first 4KB of row)
__global__ __launch_bounds__(256) void k_softmax(float* __restrict__ S) {
    float* row = S + (long long)blockIdx.x * TV_;
    u16* prow = (u16*)row;
    int t = threadIdx.x;
    float4 a = *(const float4*)(row + t * 4);
    float4 c = *(const float4*)(row + 1024 + t * 4);
    float m = fmaxf(fmaxf(fmaxf(a.x, a.y), fmaxf(a.z, a.w)),
                    fmaxf(fmaxf(c.x, c.y), fmaxf(c.z, c.w)));
#pragma unroll
    for (int o = 32; o; o >>= 1) m = fmaxf(m, __shfl_xor(m, o));
    __shared__ float rm[4], rs[4];
    if ((t & 63) == 0) rm[t >> 6] = m;
    __syncthreads();
    m = fmaxf(fmaxf(rm[0], rm[1]), fmaxf(rm[2], rm[3]));
    float e0 = __expf(a.x - m), e1 = __expf(a.y - m), e2 = __expf(a.z - m), e3 = __expf(a.w - m);
    float e4 = __expf(c.x - m), e5 = __expf(c.y - m), e6 = __expf(c.z - m), e7 = __expf(c.w - m);
    float s = ((e0 + e1) + (e2 + e3)) + ((e4 + e5) + (e6 + e7));
#pragma unroll
    for (int o = 32; o; o >>= 1) s += __shfl_xor(s, o);
    if ((t & 63) == 0) rs[t >> 6] = s;
    __syncthreads();
    s = rs[0] + rs[1] + rs[2] + rs[3];
    float inv = 1.f / s;
    ushort4 o0, o1;
    o0.x = f2h(e0 * inv); o0.y = f2h(e1 * inv); o0.z = f2h(e2 * inv); o0.w = f2h(e3 * inv);
    o1.x = f2h(e4 * inv); o1.y = f2h(e5 * inv); o1.z = f2h(e6 * inv); o1.w = f2h(e7 * inv);
    __syncthreads();   // all reads of this row's fp32 data done before overwrite
    *(ushort4*)(prow + t * 4) = o0;
    *(ushort4*)(prow + 1024 + t * 4) = o1;
}

// in-place LayerNorm over rows of 1024 fp32
__global__ __launch_bounds__(256) void k_layernorm(float* __restrict__ O,
                                                   const float* __restrict__ g,
                                                   const float* __restrict__ b) {
    float* row = O + (long long)blockIdx.x * H_;
    int t = threadIdx.x;
    float4 x = *(const float4*)(row + t * 4);
    float s1 = x.x + x.y + x.z + x.w;
    float s2 = x.x * x.x + x.y * x.y + x.z * x.z + x.w * x.w;
#pragma unroll
    for (int o = 32; o; o >>= 1) { s1 += __shfl_xor(s1, o); s2 += __shfl_xor(s2, o); }
    __shared__ float r1[4], r2[4];
    if ((t & 63) == 0) { r1[t >> 6] = s1; r2[t >> 6] = s2; }
    __syncthreads();
    s1 = r1[0] + r1[1] + r1[2] + r1[3];
    s2 = r2[0] + r2[1] + r2[2] + r2[3];
    float mean = s1 * (1.f / H_);
    float var = s2 * (1.f / H_) - mean * mean;
    float rstd = rsqrtf(fmaxf(var, 0.f) + 1e-5f);
    float4 gv = *(const float4*)(g + t * 4);
    float4 bv = *(const float4*)(b + t * 4);
    float4 o;
    o.x = (x.x - mean) * rstd * gv.x + bv.x;
    o.y = (x.y - mean) * rstd * gv.y + bv.y;
    o.z = (x.z - mean) * rstd * gv.z + bv.z;
    o.w = (x.w - mean) * rstd * gv.w + bv.w;
    *(float4*)(row + t * 4) = o;
}

extern "C" void kernel_launch(void* const* d_in, const int* in_sizes, int n_in,
                              void* d_out, int out_size, void* d_ws, size_t ws_size,
                              hipStream_t stream) {
    const float* q     = (const float*)d_in[0];
    const float* v     = (const float*)d_in[1];
    const float* W     = (const float*)d_in[2];
    const float* bias  = (const float*)d_in[3];
    const float* gamma = (const float*)d_in[4];
    const float* beta  = (const float*)d_in[5];
    float* out = (float*)d_out;
    char* ws = (char*)d_ws;

    const long long nQV = (long long)B_ * TQ_ * H_;     // 16,777,216
    const long long nW  = (long long)H_ * 2 * H_;       //  2,097,152

    u16* Qh  = (u16*)ws;         // 32 MiB fp16 query [B*TQ][1024]
    u16* Vh  = Qh + nQV;         // 32 MiB fp16 value [B][TV][1024]
    u16* Wh  = Vh + nQV;         //  4 MiB fp16 W [1024][2048]
    u16* VWT = Wh + nW;          // 32 MiB fp16 (V.Wc^T)^T : [B][1024][TV]
    u16* QW  = VWT + nQV;        // 32 MiB fp16 Q.Wq^T : [B*TQ][1024]
    float* S = (float*)(QW + nQV);   // Zc x 16 MiB fp32 scores (P fp16 in place)
    size_t fixedBytes = (size_t)((char*)S - ws);
    const size_t perZ = (size_t)TQ_ * TV_ * 4;

    int Zc = 1;
    for (int cand = 4; cand >= 1; cand >>= 1) {
        if (fixedBytes + (size_t)cand * perZ <= ws_size) { Zc = cand; break; }
    }

    // converts (all plain fp32->fp16)
    k_cvt<<<dim3(nQV / 4 / 256), dim3(256), 0, stream>>>((const float4*)q, (ushort4*)Qh);
    k_cvt<<<dim3(nQV / 4 / 256), dim3(256), 0, stream>>>((const float4*)v, (ushort4*)Vh);
    k_cvt<<<dim3(nW / 4 / 256),  dim3(256), 0, stream>>>((const float4*)W, (ushort4*)Wh);

    // VWT[z][n][v] = sum_h Wc[n,h] V[z,v,h]   (A=Wc lda=2048, B=Vh ldb=1024)
    k_gemm8<2, 1, 2048, 1024, 1024><<<dim3(256), dim3(512), 0, stream>>>(
        Wh, Vh, 0, (long long)TV_ * H_,
        32, 8, VWT, (long long)H_ * TV_, TV_, nullptr, nullptr);

    // QW = Q.Wq^T fp16  (A=Qh lda=1024, B=Wq=Wh+1024 ldb=2048)
    k_gemm8<2, 1, 1024, 2048, 1024><<<dim3(256), dim3(512), 0, stream>>>(
        Qh, Wh + H_, 0, 0,
        256, 4, QW, 0, H_, nullptr, nullptr);

    for (int c0 = 0; c0 < B_; c0 += Zc) {
        // scores S = Q.V^T  (BN=256, grid Zc*64, K=1024)
        k_gemm8<2, 0, 1024, 1024, 1024><<<dim3(Zc * 64), dim3(512), 0, stream>>>(
            Qh + (long long)c0 * TQ_ * H_, Vh + (long long)c0 * TV_ * H_,
            (long long)TQ_ * H_, (long long)TV_ * H_,
            64, 8, S, (long long)TQ_ * TV_, TV_, nullptr, nullptr);
        // softmax -> fp16 P in place over S
        k_softmax<<<dim3(Zc * TQ_), dim3(256), 0, stream>>>(S);
        // out = P.VWT + bias + QW  (BN=128, A=in-place P lda=4096, K=2048; fp32 out)
        k_gemm8<1, 2, 4096, 2048, 2048><<<dim3(Zc * 64), dim3(512), 0, stream>>>(
            (const u16*)S, VWT + (long long)c0 * H_ * TV_,
            (long long)TQ_ * 4096, (long long)H_ * TV_,
            64, 8, out + (long long)c0 * TQ_ * H_, (long long)TQ_ * H_, H_,
            bias, QW + (long long)c0 * TQ_ * H_);
    }

    k_layernorm<<<dim3(B_ * TQ_), dim3(256), 0, stream>>>(out, gamma, beta);
}

// Round 10
// 323.077 us; speedup vs baseline: 1.0023x; 1.0022x over previous
//
#include <hip/hip_runtime.h>

typedef unsigned short u16;
typedef _Float16 f16;
typedef __attribute__((ext_vector_type(8))) _Float16 f16x8;
typedef __attribute__((ext_vector_type(4))) float f32x4;

#define B_  8
#define TQ_ 2048
#define TV_ 2048
#define H_  1024

__device__ __forceinline__ u16 f2h(float x) {
    union { f16 h; u16 u; } c; c.h = (f16)x; return c.u;
}
__device__ __forceinline__ float h2f(u16 u) {
    union { u16 u; f16 h; } c; c.u = u; return (float)c.h;
}

__device__ __forceinline__ void gload_lds16(const u16* g, u16* l) {
    typedef __attribute__((address_space(1))) const unsigned short GAS;
    typedef __attribute__((address_space(3))) unsigned short LAS;
    __builtin_amdgcn_global_load_lds((GAS*)g, (LAS*)l, 16, 0, 0);
}

// fp32 -> fp16 contiguous convert
__global__ __launch_bounds__(256) void k_cvt(const float4* __restrict__ x,
                                             ushort4* __restrict__ o) {
    long long i = (long long)blockIdx.x * 256 + threadIdx.x;
    float4 v = x[i];
    ushort4 h;
    h.x = f2h(v.x); h.y = f2h(v.y); h.z = f2h(v.z); h.w = f2h(v.w);
    o[i] = h;
}

#define SBAR() __builtin_amdgcn_sched_barrier(0)

// BM=256, BN=NH*128, BK=64, 8 waves (2M x 4N), double-buffered LDS,
// 2 barriers per K-tile, read-ahead ds_reads, counted vmcnt after the last
// MFMA cluster, setprio, st-swizzled LDS via pre-swizzled global src.
// Static LDA/LDB/K. 1D grid, XCD-compact (z,bm,bn) decode.
// OM: 0 = f32 out (+bias), 1 = f16 out, 2 = f32 out (+bias + fp16 qadd).
template<int NH, int OM, int LDA, int LDB, int KK>
__global__ __launch_bounds__(512, 2) void k_gemm8(const u16* __restrict__ Ap,
                                                  const u16* __restrict__ Bp,
                                                  long long sA, long long sB,
                                                  int mnTiles, int gn,
                                                  void* __restrict__ Cv, long long sC,
                                                  int ldc, const float* __restrict__ bias,
                                                  const u16* __restrict__ qadd) {
    constexpr int BUFU = 16384 + NH * 8192;
    constexpr int NT = KK / 64;
    __shared__ __align__(16) u16 lds[2 * BUFU];

    const int nper = gridDim.x >> 3;
    const int g = (blockIdx.x & 7) * nper + (blockIdx.x >> 3);
    const int z = g / mnTiles;
    const int rem = g - z * mnTiles;
    const int bm = (rem / gn) * 256;
    const int bn = (rem % gn) * (NH * 128);

    const int tid = threadIdx.x;
    const int lane = tid & 63, wid = tid >> 6;
    const int wm = wid >> 2, wn = wid & 3;
    const int l16 = lane & 15, kg = lane >> 4;

    f32x4 acc[8][NH * 2];
    f32x4 zv = {0.f, 0.f, 0.f, 0.f};
#pragma unroll
    for (int i = 0; i < 8; ++i)
#pragma unroll
        for (int j = 0; j < NH * 2; ++j) acc[i][j] = zv;

    const u16* Ab = Ap + (long long)z * sA;
    const u16* Bb = Bp + (long long)z * sB;

    const int jst = (tid & 7) ^ ((tid >> 3) & 7);
    const int rst = tid >> 3;

    auto stageA = [&](int k0, int h, int obase) {
#pragma unroll
        for (int c = 0; c < 2; ++c) {
            int r = h * 128 + c * 64 + rst;
            gload_lds16(Ab + (long long)(bm + r) * LDA + k0 + jst * 8,
                        &lds[obase + h * 8192 + c * 4096 + tid * 8]);
        }
    };
    auto stageB = [&](int k0, int h, int rbase) {
#pragma unroll
        for (int c = 0; c < 2; ++c) {
            int r = h * 128 + c * 64 + rst;
            gload_lds16(Bb + (long long)(bn + r) * LDB + k0 + jst * 8,
                        &lds[rbase + h * 8192 + c * 4096 + tid * 8]);
        }
    };
    auto rdA = [&](int base, int mh, f16x8* dst) {
#pragma unroll
        for (int i = 0; i < 4; ++i) {
            int r = wm * 128 + mh * 64 + i * 16 + l16;
#pragma unroll
            for (int ks = 0; ks < 2; ++ks) {
                int js = (ks * 4 + kg) ^ (r & 7);
                dst[i * 2 + ks] = *(const f16x8*)&lds[base + r * 64 + js * 8];
            }
        }
    };
    auto rdB = [&](int base, int nh, f16x8* dst) {
#pragma unroll
        for (int jn = 0; jn < 2; ++jn) {
            int r = wn * (NH * 32) + nh * 32 + jn * 16 + l16;
#pragma unroll
            for (int ks = 0; ks < 2; ++ks) {
                int js = (ks * 4 + kg) ^ (r & 7);
                dst[jn * 2 + ks] = *(const f16x8*)&lds[base + r * 64 + js * 8];
            }
        }
    };

    // ---- prologue: tile0 (A+B) -> buf0; tile1 B -> buf1
    stageA(0, 0, 0);
    stageA(0, 1, 0);
#pragma unroll
    for (int h = 0; h < NH; ++h) stageB(0, h, 16384);
    if (NT > 1) {
#pragma unroll
        for (int h = 0; h < NH; ++h) stageB(64, h, BUFU + 16384);
        if constexpr (NH == 2) asm volatile("s_waitcnt vmcnt(4)" ::: "memory");
        else                   asm volatile("s_waitcnt vmcnt(2)" ::: "memory");
    } else {
        asm volatile("s_waitcnt vmcnt(0)" ::: "memory");
    }
    __builtin_amdgcn_s_barrier();
    SBAR();

    f16x8 a0[8], a1[8], b0[4], b1[4];
#pragma unroll 1
    for (int t = 0; t < NT; ++t) {
        const int cur = t & 1;
        const int AB = cur * BUFU;
        const int BB = AB + 16384;
        const int OA = (cur ^ 1) * BUFU;
        const bool sa = (t + 1) < NT;
        const bool sb = (t + 2) < NT;
        if constexpr (NH == 2) {
            // ph1: read a0,b0 (deps) + b1 (ahead); stage A0,A1(t+1); MFMA q00+q01
            rdA(AB, 0, a0);
            rdB(BB, 0, b0);
            rdB(BB, 1, b1);
            if (sa) {
                stageA((t + 1) * 64, 0, OA);
                stageA((t + 1) * 64, 1, OA);
            }
            SBAR();
            __builtin_amdgcn_s_setprio(1);
#pragma unroll
            for (int i = 0; i < 4; ++i)
#pragma unroll
                for (int jn = 0; jn < 2; ++jn)
#pragma unroll
                    for (int ks = 0; ks < 2; ++ks)
                        acc[i][jn] = __builtin_amdgcn_mfma_f32_16x16x32_f16(a0[i * 2 + ks], b0[jn * 2 + ks], acc[i][jn], 0, 0, 0);
#pragma unroll
            for (int i = 0; i < 4; ++i)
#pragma unroll
                for (int jn = 0; jn < 2; ++jn)
#pragma unroll
                    for (int ks = 0; ks < 2; ++ks)
                        acc[i][2 + jn] = __builtin_amdgcn_mfma_f32_16x16x32_f16(a0[i * 2 + ks], b1[jn * 2 + ks], acc[i][2 + jn], 0, 0, 0);
            __builtin_amdgcn_s_setprio(0);
            __builtin_amdgcn_s_barrier();
            SBAR();
            // ph2: read a1; stage B0,B1(t+2) over consumed B(t); MFMA q11+q10; vmcnt
            rdA(AB, 1, a1);
            if (sb) {
                stageB((t + 2) * 64, 0, BB);
                stageB((t + 2) * 64, 1, BB);
            }
            SBAR();
            __builtin_amdgcn_s_setprio(1);
#pragma unroll
            for (int i = 0; i < 4; ++i)
#pragma unroll
                for (int jn = 0; jn < 2; ++jn)
#pragma unroll
                    for (int ks = 0; ks < 2; ++ks)
                        acc[4 + i][2 + jn] = __builtin_amdgcn_mfma_f32_16x16x32_f16(a1[i * 2 + ks], b1[jn * 2 + ks], acc[4 + i][2 + jn], 0, 0, 0);
#pragma unroll
            for (int i = 0; i < 4; ++i)
#pragma unroll
                for (int jn = 0; jn < 2; ++jn)
#pragma unroll
                    for (int ks = 0; ks < 2; ++ks)
                        acc[4 + i][jn] = __builtin_amdgcn_mfma_f32_16x16x32_f16(a1[i * 2 + ks], b0[jn * 2 + ks], acc[4 + i][jn], 0, 0, 0);
            __builtin_amdgcn_s_setprio(0);
            if (sb)      asm volatile("s_waitcnt vmcnt(4)" ::: "memory");
            else if (sa) asm volatile("s_waitcnt vmcnt(0)" ::: "memory");
            __builtin_amdgcn_s_barrier();
            SBAR();
        } else {
            // ph1: read a0,b0 (deps) + a1 (ahead); stage A0,A1(t+1); MFMA half 0
            rdA(AB, 0, a0);
            rdB(BB, 0, b0);
            rdA(AB, 1, a1);
            if (sa) {
                stageA((t + 1) * 64, 0, OA);
                stageA((t + 1) * 64, 1, OA);
            }
            SBAR();
            __builtin_amdgcn_s_setprio(1);
#pragma unroll
            for (int i = 0; i < 4; ++i)
#pragma unroll
                for (int jn = 0; jn < 2; ++jn)
#pragma unroll
                    for (int ks = 0; ks < 2; ++ks)
                        acc[i][jn] = __builtin_amdgcn_mfma_f32_16x16x32_f16(a0[i * 2 + ks], b0[jn * 2 + ks], acc[i][jn], 0, 0, 0);
            __builtin_amdgcn_s_setprio(0);
            __builtin_amdgcn_s_barrier();
            SBAR();
            // ph2: stage B(t+2) over consumed B(t); MFMA half 1; vmcnt
            if (sb) stageB((t + 2) * 64, 0, BB);
            SBAR();
            __builtin_amdgcn_s_setprio(1);
#pragma unroll
            for (int i = 0; i < 4; ++i)
#pragma unroll
                for (int jn = 0; jn < 2; ++jn)
#pragma unroll
                    for (int ks = 0; ks < 2; ++ks)
                        acc[4 + i][jn] = __builtin_amdgcn_mfma_f32_16x16x32_f16(a1[i * 2 + ks], b0[jn * 2 + ks], acc[4 + i][jn], 0, 0, 0);
            __builtin_amdgcn_s_setprio(0);
            if (sb)      asm volatile("s_waitcnt vmcnt(2)" ::: "memory");
            else if (sa) asm volatile("s_waitcnt vmcnt(0)" ::: "memory");
            __builtin_amdgcn_s_barrier();
            SBAR();
        }
    }

    // ---- epilogue
    const int colBase = bn + wn * (NH * 32);
    const int rowBase = bm + wm * 128;
#pragma unroll
    for (int mi = 0; mi < 8; ++mi) {
#pragma unroll
        for (int nj = 0; nj < NH * 2; ++nj) {
            int col = colBase + nj * 16 + l16;
            float badd = (OM != 1 && bias) ? bias[col] : 0.f;
#pragma unroll
            for (int r = 0; r < 4; ++r) {
                long long row = rowBase + mi * 16 + kg * 4 + r;
                long long idx = (long long)z * sC + row * (long long)ldc + col;
                float vv = acc[mi][nj][r] + badd;
                if constexpr (OM == 1) {
                    ((u16*)Cv)[idx] = f2h(vv);
                } else if constexpr (OM == 2) {
                    ((float*)Cv)[idx] = vv + h2f(qadd[idx]);
                } else {
                    ((float*)Cv)[idx] = vv;
                }
            }
        }
    }
}

// row softmax: fp32 scores [*, 2048] -> fp16 probs IN PLACE (first 4KB of row)
__global__ __launch_bounds__(256) void k_softmax(float* __restrict__ S) {
    float* row = S + (long long)blockIdx.x * TV_;
    u16* prow = (u16*)row;
    int t = threadIdx.x;
    float4 a = *(const float4*)(row + t * 4);
    float4 c = *(const float4*)(row + 1024 + t * 4);
    float m = fmaxf(fmaxf(fmaxf(a.x, a.y), fmaxf(a.z, a.w)),
                    fmaxf(fmaxf(c.x, c.y), fmaxf(c.z, c.w)));
#pragma unroll
    for (int o = 32; o; o >>= 1) m = fmaxf(m, __shfl_xor(m, o));
    __shared__ float rm[4], rs[4];
    if ((t & 63) == 0) rm[t >> 6] = m;
    __syncthreads();
    m = fmaxf(fmaxf(rm[0], rm[1]), fmaxf(rm[2], rm[3]));
    float e0 = __expf(a.x - m), e1 = __expf(a.y - m), e2 = __expf(a.z - m), e3 = __expf(a.w - m);
    float e4 = __expf(c.x - m), e5 = __expf(c.y - m), e6 = __expf(c.z - m), e7 = __expf(c.w - m);
    float s = ((e0 + e1) + (e2 + e3)) + ((e4 + e5) + (e6 + e7));
#pragma unroll
    for (int o = 32; o; o >>= 1) s += __shfl_xor(s, o);
    if ((t & 63) == 0) rs[t >> 6] = s;
    __syncthreads();
    s = rs[0] + rs[1] + rs[2] + rs[3];
    float inv = 1.f / s;
    ushort4 o0, o1;
    o0.x = f2h(e0 * inv); o0.y = f2h(e1 * inv); o0.z = f2h(e2 * inv); o0.w = f2h(e3 * inv);
    o1.x = f2h(e4 * inv); o1.y = f2h(e5 * inv); o1.z = f2h(e6 * inv); o1.w = f2h(e7 * inv);
    __syncthreads();   // all reads of this row's fp32 data done before overwrite
    *(ushort4*)(prow + t * 4) = o0;
    *(ushort4*)(prow + 1024 + t * 4) = o1;
}

// in-place LayerNorm over rows of 1024 fp32
__global__ __launch_bounds__(256) void k_layernorm(float* __restrict__ O,
                                                   const float* __restrict__ g,
                                                   const float* __restrict__ b) {
    float* row = O + (long long)blockIdx.x * H_;
    int t = threadIdx.x;
    float4 x = *(const float4*)(row + t * 4);
    float s1 = x.x + x.y + x.z + x.w;
    float s2 = x.x * x.x + x.y * x.y + x.z * x.z + x.w * x.w;
#pragma unroll
    for (int o = 32; o; o >>= 1) { s1 += __shfl_xor(s1, o); s2 += __shfl_xor(s2, o); }
    __shared__ float r1[4], r2[4];
    if ((t & 63) == 0) { r1[t >> 6] = s1; r2[t >> 6] = s2; }
    __syncthreads();
    s1 = r1[0] + r1[1] + r1[2] + r1[3];
    s2 = r2[0] + r2[1] + r2[2] + r2[3];
    float mean = s1 * (1.f / H_);
    float var = s2 * (1.f / H_) - mean * mean;
    float rstd = rsqrtf(fmaxf(var, 0.f) + 1e-5f);
    float4 gv = *(const float4*)(g + t * 4);
    float4 bv = *(const float4*)(b + t * 4);
    float4 o;
    o.x = (x.x - mean) * rstd * gv.x + bv.x;
    o.y = (x.y - mean) * rstd * gv.y + bv.y;
    o.z = (x.z - mean) * rstd * gv.z + bv.z;
    o.w = (x.w - mean) * rstd * gv.w + bv.w;
    *(float4*)(row + t * 4) = o;
}

extern "C" void kernel_launch(void* const* d_in, const int* in_sizes, int n_in,
                              void* d_out, int out_size, void* d_ws, size_t ws_size,
                              hipStream_t stream) {
    const float* q     = (const float*)d_in[0];
    const float* v     = (const float*)d_in[1];
    const float* W     = (const float*)d_in[2];
    const float* bias  = (const float*)d_in[3];
    const float* gamma = (const float*)d_in[4];
    const float* beta  = (const float*)d_in[5];
    float* out = (float*)d_out;
    char* ws = (char*)d_ws;

    const long long nQV = (long long)B_ * TQ_ * H_;     // 16,777,216
    const long long nW  = (long long)H_ * 2 * H_;       //  2,097,152

    u16* Qh  = (u16*)ws;         // 32 MiB fp16 query [B*TQ][1024]
    u16* Vh  = Qh + nQV;         // 32 MiB fp16 value [B][TV][1024]
    u16* Wh  = Vh + nQV;         //  4 MiB fp16 W [1024][2048]
    u16* VWT = Wh + nW;          // 32 MiB fp16 (V.Wc^T)^T : [B][1024][TV]
    u16* QW  = VWT + nQV;        // 32 MiB fp16 Q.Wq^T : [B*TQ][1024]
    float* S = (float*)(QW + nQV);   // Zc x 16 MiB fp32 scores (P fp16 in place)
    size_t fixedBytes = (size_t)((char*)S - ws);
    const size_t perZ = (size_t)TQ_ * TV_ * 4;

    int Zc = 1;
    for (int cand = 4; cand >= 1; cand >>= 1) {
        if (fixedBytes + (size_t)cand * perZ <= ws_size) { Zc = cand; break; }
    }

    // converts (all plain fp32->fp16)
    k_cvt<<<dim3(nQV / 4 / 256), dim3(256), 0, stream>>>((const float4*)q, (ushort4*)Qh);
    k_cvt<<<dim3(nQV / 4 / 256), dim3(256), 0, stream>>>((const float4*)v, (ushort4*)Vh);
    k_cvt<<<dim3(nW / 4 / 256),  dim3(256), 0, stream>>>((const float4*)W, (ushort4*)Wh);

    // VWT[z][n][v] = sum_h Wc[n,h] V[z,v,h]   (A=Wc lda=2048, B=Vh ldb=1024)
    k_gemm8<2, 1, 2048, 1024, 1024><<<dim3(256), dim3(512), 0, stream>>>(
        Wh, Vh, 0, (long long)TV_ * H_,
        32, 8, VWT, (long long)H_ * TV_, TV_, nullptr, nullptr);

    // QW = Q.Wq^T fp16  (A=Qh lda=1024, B=Wq=Wh+1024 ldb=2048)
    k_gemm8<2, 1, 1024, 2048, 1024><<<dim3(256), dim3(512), 0, stream>>>(
        Qh, Wh + H_, 0, 0,
        256, 4, QW, 0, H_, nullptr, nullptr);

    for (int c0 = 0; c0 < B_; c0 += Zc) {
        // scores S = Q.V^T  (BN=256, grid Zc*64, K=1024)
        k_gemm8<2, 0, 1024, 1024, 1024><<<dim3(Zc * 64), dim3(512), 0, stream>>>(
            Qh + (long long)c0 * TQ_ * H_, Vh + (long long)c0 * TV_ * H_,
            (long long)TQ_ * H_, (long long)TV_ * H_,
            64, 8, S, (long long)TQ_ * TV_, TV_, nullptr, nullptr);
        // softmax -> fp16 P in place over S
        k_softmax<<<dim3(Zc * TQ_), dim3(256), 0, stream>>>(S);
        // out = P.VWT + bias + QW  (BN=128, A=in-place P lda=4096, K=2048; fp32 out)
        k_gemm8<1, 2, 4096, 2048, 2048><<<dim3(Zc * 64), dim3(512), 0, stream>>>(
            (const u16*)S, VWT + (long long)c0 * H_ * TV_,
            (long long)TQ_ * 4096, (long long)H_ * TV_,
            64, 8, out + (long long)c0 * TQ_ * H_, (long long)TQ_ * H_, H_,
            bias, QW + (long long)c0 * TQ_ * H_);
    }

    k_layernorm<<<dim3(B_ * TQ_), dim3(256), 0, stream>>>(out, gamma, beta);
}

// Round 11
// 322.987 us; speedup vs baseline: 1.0025x; 1.0003x over previous
//
#include <hip/hip_runtime.h>

typedef unsigned short u16;
typedef _Float16 f16;
typedef __attribute__((ext_vector_type(8))) _Float16 f16x8;
typedef __attribute__((ext_vector_type(4))) float f32x4;

#define B_  8
#define TQ_ 2048
#define TV_ 2048
#define H_  1024

__device__ __forceinline__ u16 f2h(float x) {
    union { f16 h; u16 u; } c; c.h = (f16)x; return c.u;
}
__device__ __forceinline__ float h2f(u16 u) {
    union { u16 u; f16 h; } c; c.u = u; return (float)c.h;
}

__device__ __forceinline__ void gload_lds16(const u16* g, u16* l) {
    typedef __attribute__((address_space(1))) const unsigned short GAS;
    typedef __attribute__((address_space(3))) unsigned short LAS;
    __builtin_amdgcn_global_load_lds((GAS*)g, (LAS*)l, 16, 0, 0);
}

// fp32 -> fp16 contiguous convert
__global__ __launch_bounds__(256) void k_cvt(const float4* __restrict__ x,
                                             ushort4* __restrict__ o) {
    long long i = (long long)blockIdx.x * 256 + threadIdx.x;
    float4 v = x[i];
    ushort4 h;
    h.x = f2h(v.x); h.y = f2h(v.y); h.z = f2h(v.z); h.w = f2h(v.w);
    o[i] = h;
}

#define SBAR() __builtin_amdgcn_sched_barrier(0)

// BM=256, BN=NH*128, BK=64, 8 waves (2M x 4N), double-buffered LDS,
// 2 barriers per K-tile, read-ahead ds_reads, counted vmcnt after the last
// MFMA cluster, setprio, st-swizzled LDS via pre-swizzled global src.
// Static LDA/LDB/K. 1D grid, XCD-compact (z,bm,bn) decode.
// OM: 0 = f32 out (+bias), 1 = f16 out, 2 = f32 out (+bias + fp16 qadd).
template<int NH, int OM, int LDA, int LDB, int KK>
__global__ __launch_bounds__(512, 2) void k_gemm8(const u16* __restrict__ Ap,
                                                  const u16* __restrict__ Bp,
                                                  long long sA, long long sB,
                                                  int mnTiles, int gn,
                                                  void* __restrict__ Cv, long long sC,
                                                  int ldc, const float* __restrict__ bias,
                                                  const u16* __restrict__ qadd) {
    constexpr int BUFU = 16384 + NH * 8192;
    constexpr int NT = KK / 64;
    __shared__ __align__(16) u16 lds[2 * BUFU];

    const int nper = gridDim.x >> 3;
    const int g = (blockIdx.x & 7) * nper + (blockIdx.x >> 3);
    const int z = g / mnTiles;
    const int rem = g - z * mnTiles;
    const int bm = (rem / gn) * 256;
    const int bn = (rem % gn) * (NH * 128);

    const int tid = threadIdx.x;
    const int lane = tid & 63, wid = tid >> 6;
    const int wm = wid >> 2, wn = wid & 3;
    const int l16 = lane & 15, kg = lane >> 4;

    f32x4 acc[8][NH * 2];
    f32x4 zv = {0.f, 0.f, 0.f, 0.f};
#pragma unroll
    for (int i = 0; i < 8; ++i)
#pragma unroll
        for (int j = 0; j < NH * 2; ++j) acc[i][j] = zv;

    const u16* Ab = Ap + (long long)z * sA;
    const u16* Bb = Bp + (long long)z * sB;

    const int jst = (tid & 7) ^ ((tid >> 3) & 7);
    const int rst = tid >> 3;

    auto stageA = [&](int k0, int h, int obase) {
#pragma unroll
        for (int c = 0; c < 2; ++c) {
            int r = h * 128 + c * 64 + rst;
            gload_lds16(Ab + (long long)(bm + r) * LDA + k0 + jst * 8,
                        &lds[obase + h * 8192 + c * 4096 + tid * 8]);
        }
    };
    auto stageB = [&](int k0, int h, int rbase) {
#pragma unroll
        for (int c = 0; c < 2; ++c) {
            int r = h * 128 + c * 64 + rst;
            gload_lds16(Bb + (long long)(bn + r) * LDB + k0 + jst * 8,
                        &lds[rbase + h * 8192 + c * 4096 + tid * 8]);
        }
    };
    auto rdA = [&](int base, int mh, f16x8* dst) {
#pragma unroll
        for (int i = 0; i < 4; ++i) {
            int r = wm * 128 + mh * 64 + i * 16 + l16;
#pragma unroll
            for (int ks = 0; ks < 2; ++ks) {
                int js = (ks * 4 + kg) ^ (r & 7);
                dst[i * 2 + ks] = *(const f16x8*)&lds[base + r * 64 + js * 8];
            }
        }
    };
    auto rdB = [&](int base, int nh, f16x8* dst) {
#pragma unroll
        for (int jn = 0; jn < 2; ++jn) {
            int r = wn * (NH * 32) + nh * 32 + jn * 16 + l16;
#pragma unroll
            for (int ks = 0; ks < 2; ++ks) {
                int js = (ks * 4 + kg) ^ (r & 7);
                dst[jn * 2 + ks] = *(const f16x8*)&lds[base + r * 64 + js * 8];
            }
        }
    };

    // ---- prologue: tile0 (A+B) -> buf0; tile1 B -> buf1
    stageA(0, 0, 0);
    stageA(0, 1, 0);
#pragma unroll
    for (int h = 0; h < NH; ++h) stageB(0, h, 16384);
    if (NT > 1) {
#pragma unroll
        for (int h = 0; h < NH; ++h) stageB(64, h, BUFU + 16384);
        if constexpr (NH == 2) asm volatile("s_waitcnt vmcnt(4)" ::: "memory");
        else                   asm volatile("s_waitcnt vmcnt(2)" ::: "memory");
    } else {
        asm volatile("s_waitcnt vmcnt(0)" ::: "memory");
    }
    __builtin_amdgcn_s_barrier();
    SBAR();

    f16x8 a0[8], a1[8], b0[4], b1[4];
#pragma unroll 1
    for (int t = 0; t < NT; ++t) {
        const int cur = t & 1;
        const int AB = cur * BUFU;
        const int BB = AB + 16384;
        const int OA = (cur ^ 1) * BUFU;
        const bool sa = (t + 1) < NT;
        const bool sb = (t + 2) < NT;
        if constexpr (NH == 2) {
            // ph1: read a0,b0 (deps) + b1 (ahead); stage A0,A1(t+1); MFMA q00+q01
            rdA(AB, 0, a0);
            rdB(BB, 0, b0);
            rdB(BB, 1, b1);
            if (sa) {
                stageA((t + 1) * 64, 0, OA);
                stageA((t + 1) * 64, 1, OA);
            }
            SBAR();
            __builtin_amdgcn_s_setprio(1);
#pragma unroll
            for (int i = 0; i < 4; ++i)
#pragma unroll
                for (int jn = 0; jn < 2; ++jn)
#pragma unroll
                    for (int ks = 0; ks < 2; ++ks)
                        acc[i][jn] = __builtin_amdgcn_mfma_f32_16x16x32_f16(a0[i * 2 + ks], b0[jn * 2 + ks], acc[i][jn], 0, 0, 0);
#pragma unroll
            for (int i = 0; i < 4; ++i)
#pragma unroll
                for (int jn = 0; jn < 2; ++jn)
#pragma unroll
                    for (int ks = 0; ks < 2; ++ks)
                        acc[i][2 + jn] = __builtin_amdgcn_mfma_f32_16x16x32_f16(a0[i * 2 + ks], b1[jn * 2 + ks], acc[i][2 + jn], 0, 0, 0);
            __builtin_amdgcn_s_setprio(0);
            __builtin_amdgcn_s_barrier();
            SBAR();
            // ph2: read a1; stage B0,B1(t+2) over consumed B(t); MFMA q11+q10; vmcnt
            rdA(AB, 1, a1);
            if (sb) {
                stageB((t + 2) * 64, 0, BB);
                stageB((t + 2) * 64, 1, BB);
            }
            SBAR();
            __builtin_amdgcn_s_setprio(1);
#pragma unroll
            for (int i = 0; i < 4; ++i)
#pragma unroll
                for (int jn = 0; jn < 2; ++jn)
#pragma unroll
                    for (int ks = 0; ks < 2; ++ks)
                        acc[4 + i][2 + jn] = __builtin_amdgcn_mfma_f32_16x16x32_f16(a1[i * 2 + ks], b1[jn * 2 + ks], acc[4 + i][2 + jn], 0, 0, 0);
#pragma unroll
            for (int i = 0; i < 4; ++i)
#pragma unroll
                for (int jn = 0; jn < 2; ++jn)
#pragma unroll
                    for (int ks = 0; ks < 2; ++ks)
                        acc[4 + i][jn] = __builtin_amdgcn_mfma_f32_16x16x32_f16(a1[i * 2 + ks], b0[jn * 2 + ks], acc[4 + i][jn], 0, 0, 0);
            __builtin_amdgcn_s_setprio(0);
            if (sb)      asm volatile("s_waitcnt vmcnt(4)" ::: "memory");
            else if (sa) asm volatile("s_waitcnt vmcnt(0)" ::: "memory");
            __builtin_amdgcn_s_barrier();
            SBAR();
        } else {
            // ph1: read a0,b0 (deps) + a1 (ahead); stage A0,A1(t+1); MFMA half 0
            rdA(AB, 0, a0);
            rdB(BB, 0, b0);
            rdA(AB, 1, a1);
            if (sa) {
                stageA((t + 1) * 64, 0, OA);
                stageA((t + 1) * 64, 1, OA);
            }
            SBAR();
            __builtin_amdgcn_s_setprio(1);
#pragma unroll
            for (int i = 0; i < 4; ++i)
#pragma unroll
                for (int jn = 0; jn < 2; ++jn)
#pragma unroll
                    for (int ks = 0; ks < 2; ++ks)
                        acc[i][jn] = __builtin_amdgcn_mfma_f32_16x16x32_f16(a0[i * 2 + ks], b0[jn * 2 + ks], acc[i][jn], 0, 0, 0);
            __builtin_amdgcn_s_setprio(0);
            __builtin_amdgcn_s_barrier();
            SBAR();
            // ph2: stage B(t+2) over consumed B(t); MFMA half 1; vmcnt
            if (sb) stageB((t + 2) * 64, 0, BB);
            SBAR();
            __builtin_amdgcn_s_setprio(1);
#pragma unroll
            for (int i = 0; i < 4; ++i)
#pragma unroll
                for (int jn = 0; jn < 2; ++jn)
#pragma unroll
                    for (int ks = 0; ks < 2; ++ks)
                        acc[4 + i][jn] = __builtin_amdgcn_mfma_f32_16x16x32_f16(a1[i * 2 + ks], b0[jn * 2 + ks], acc[4 + i][jn], 0, 0, 0);
            __builtin_amdgcn_s_setprio(0);
            if (sb)      asm volatile("s_waitcnt vmcnt(2)" ::: "memory");
            else if (sa) asm volatile("s_waitcnt vmcnt(0)" ::: "memory");
            __builtin_amdgcn_s_barrier();
            SBAR();
        }
    }

    // ---- epilogue
    const int colBase = bn + wn * (NH * 32);
    const int rowBase = bm + wm * 128;
#pragma unroll
    for (int mi = 0; mi < 8; ++mi) {
#pragma unroll
        for (int nj = 0; nj < NH * 2; ++nj) {
            int col = colBase + nj * 16 + l16;
            float badd = (OM != 1 && bias) ? bias[col] : 0.f;
#pragma unroll
            for (int r = 0; r < 4; ++r) {
                long long row = rowBase + mi * 16 + kg * 4 + r;
                long long idx = (long long)z * sC + row * (long long)ldc + col;
                float vv = acc[mi][nj][r] + badd;
                if constexpr (OM == 1) {
                    ((u16*)Cv)[idx] = f2h(vv);
                } else if constexpr (OM == 2) {
                    ((float*)Cv)[idx] = vv + h2f(qadd[idx]);
                } else {
                    ((float*)Cv)[idx] = vv;
                }
            }
        }
    }
}

// row softmax: fp32 scores [*, 2048] -> fp16 probs IN PLACE (first 4KB of row)
__global__ __launch_bounds__(256) void k_softmax(float* __restrict__ S) {
    float* row = S + (long long)blockIdx.x * TV_;
    u16* prow = (u16*)row;
    int t = threadIdx.x;
    float4 a = *(const float4*)(row + t * 4);
    float4 c = *(const float4*)(row + 1024 + t * 4);
    float m = fmaxf(fmaxf(fmaxf(a.x, a.y), fmaxf(a.z, a.w)),
                    fmaxf(fmaxf(c.x, c.y), fmaxf(c.z, c.w)));
#pragma unroll
    for (int o = 32; o; o >>= 1) m = fmaxf(m, __shfl_xor(m, o));
    __shared__ float rm[4], rs[4];
    if ((t & 63) == 0) rm[t >> 6] = m;
    __syncthreads();
    m = fmaxf(fmaxf(rm[0], rm[1]), fmaxf(rm[2], rm[3]));
    float e0 = __expf(a.x - m), e1 = __expf(a.y - m), e2 = __expf(a.z - m), e3 = __expf(a.w - m);
    float e4 = __expf(c.x - m), e5 = __expf(c.y - m), e6 = __expf(c.z - m), e7 = __expf(c.w - m);
    float s = ((e0 + e1) + (e2 + e3)) + ((e4 + e5) + (e6 + e7));
#pragma unroll
    for (int o = 32; o; o >>= 1) s += __shfl_xor(s, o);
    if ((t & 63) == 0) rs[t >> 6] = s;
    __syncthreads();
    s = rs[0] + rs[1] + rs[2] + rs[3];
    float inv = 1.f / s;
    ushort4 o0, o1;
    o0.x = f2h(e0 * inv); o0.y = f2h(e1 * inv); o0.z = f2h(e2 * inv); o0.w = f2h(e3 * inv);
    o1.x = f2h(e4 * inv); o1.y = f2h(e5 * inv); o1.z = f2h(e6 * inv); o1.w = f2h(e7 * inv);
    __syncthreads();   // all reads of this row's fp32 data done before overwrite
    *(ushort4*)(prow + t * 4) = o0;
    *(ushort4*)(prow + 1024 + t * 4) = o1;
}

// in-place LayerNorm over rows of 1024 fp32
__global__ __launch_bounds__(256) void k_layernorm(float* __restrict__ O,
                                                   const float* __restrict__ g,
                                                   const float* __restrict__ b) {
    float* row = O + (long long)blockIdx.x * H_;
    int t = threadIdx.x;
    float4 x = *(const float4*)(row + t * 4);
    float s1 = x.x + x.y + x.z + x.w;
    float s2 = x.x * x.x + x.y * x.y + x.z * x.z + x.w * x.w;
#pragma unroll
    for (int o = 32; o; o >>= 1) { s1 += __shfl_xor(s1, o); s2 += __shfl_xor(s2, o); }
    __shared__ float r1[4], r2[4];
    if ((t & 63) == 0) { r1[t >> 6] = s1; r2[t >> 6] = s2; }
    __syncthreads();
    s1 = r1[0] + r1[1] + r1[2] + r1[3];
    s2 = r2[0] + r2[1] + r2[2] + r2[3];
    float mean = s1 * (1.f / H_);
    float var = s2 * (1.f / H_) - mean * mean;
    float rstd = rsqrtf(fmaxf(var, 0.f) + 1e-5f);
    float4 gv = *(const float4*)(g + t * 4);
    float4 bv = *(const float4*)(b + t * 4);
    float4 o;
    o.x = (x.x - mean) * rstd * gv.x + bv.x;
    o.y = (x.y - mean) * rstd * gv.y + bv.y;
    o.z = (x.z - mean) * rstd * gv.z + bv.z;
    o.w = (x.w - mean) * rstd * gv.w + bv.w;
    *(float4*)(row + t * 4) = o;
}

extern "C" void kernel_launch(void* const* d_in, const int* in_sizes, int n_in,
                              void* d_out, int out_size, void* d_ws, size_t ws_size,
                              hipStream_t stream) {
    const float* q     = (const float*)d_in[0];
    const float* v     = (const float*)d_in[1];
    const float* W     = (const float*)d_in[2];
    const float* bias  = (const float*)d_in[3];
    const float* gamma = (const float*)d_in[4];
    const float* beta  = (const float*)d_in[5];
    float* out = (float*)d_out;
    char* ws = (char*)d_ws;

    const long long nQV = (long long)B_ * TQ_ * H_;     // 16,777,216
    const long long nW  = (long long)H_ * 2 * H_;       //  2,097,152

    u16* Qh  = (u16*)ws;         // 32 MiB fp16 query [B*TQ][1024]
    u16* Vh  = Qh + nQV;         // 32 MiB fp16 value [B][TV][1024]
    u16* Wh  = Vh + nQV;         //  4 MiB fp16 W [1024][2048]
    u16* VWT = Wh + nW;          // 32 MiB fp16 (V.Wc^T)^T : [B][1024][TV]
    u16* QW  = VWT + nQV;        // 32 MiB fp16 Q.Wq^T : [B*TQ][1024]
    float* S = (float*)(QW + nQV);   // Zc x 16 MiB fp32 scores (P fp16 in place)
    size_t fixedBytes = (size_t)((char*)S - ws);
    const size_t perZ = (size_t)TQ_ * TV_ * 4;

    int Zc = 1;
    for (int cand = 4; cand >= 1; cand >>= 1) {
        if (fixedBytes + (size_t)cand * perZ <= ws_size) { Zc = cand; break; }
    }

    // converts (all plain fp32->fp16)
    k_cvt<<<dim3(nQV / 4 / 256), dim3(256), 0, stream>>>((const float4*)q, (ushort4*)Qh);
    k_cvt<<<dim3(nQV / 4 / 256), dim3(256), 0, stream>>>((const float4*)v, (ushort4*)Vh);
    k_cvt<<<dim3(nW / 4 / 256),  dim3(256), 0, stream>>>((const float4*)W, (ushort4*)Wh);

    // VWT[z][n][v] = sum_h Wc[n,h] V[z,v,h]   (A=Wc lda=2048, B=Vh ldb=1024)
    k_gemm8<2, 1, 2048, 1024, 1024><<<dim3(256), dim3(512), 0, stream>>>(
        Wh, Vh, 0, (long long)TV_ * H_,
        32, 8, VWT, (long long)H_ * TV_, TV_, nullptr, nullptr);

    // QW = Q.Wq^T fp16  (A=Qh lda=1024, B=Wq=Wh+1024 ldb=2048)
    k_gemm8<2, 1, 1024, 2048, 1024><<<dim3(256), dim3(512), 0, stream>>>(
        Qh, Wh + H_, 0, 0,
        256, 4, QW, 0, H_, nullptr, nullptr);

    for (int c0 = 0; c0 < B_; c0 += Zc) {
        // scores S = Q.V^T  (BN=256, grid Zc*64, K=1024)
        k_gemm8<2, 0, 1024, 1024, 1024><<<dim3(Zc * 64), dim3(512), 0, stream>>>(
            Qh + (long long)c0 * TQ_ * H_, Vh + (long long)c0 * TV_ * H_,
            (long long)TQ_ * H_, (long long)TV_ * H_,
            64, 8, S, (long long)TQ_ * TV_, TV_, nullptr, nullptr);
        // softmax -> fp16 P in place over S
        k_softmax<<<dim3(Zc * TQ_), dim3(256), 0, stream>>>(S);
        // out = P.VWT + bias + QW  (BN=128, A=in-place P lda=4096, K=2048; fp32 out)
        k_gemm8<1, 2, 4096, 2048, 2048><<<dim3(Zc * 64), dim3(512), 0, stream>>>(
            (const u16*)S, VWT + (long long)c0 * H_ * TV_,
            (long long)TQ_ * 4096, (long long)H_ * TV_,
            64, 8, out + (long long)c0 * TQ_ * H_, (long long)TQ_ * H_, H_,
            bias, QW + (long long)c0 * TQ_ * H_);
    }

    k_layernorm<<<dim3(B_ * TQ_), dim3(256), 0, stream>>>(out, gamma, beta);
}